// Round 6
// baseline (806.323 us; speedup 1.0000x reference)
//
#include <hip/hip_runtime.h>
#include <hip/hip_bf16.h>
#include <math.h>

// Problem constants
#define NM 1024         // molecules
#define NA 32           // atoms per molecule
#define ZD 64           // z dim
#define HD 256          // hidden
#define AT 10           // atom types
#define BT 5            // bond types
#define NROWS (NM*NA)   // 32768
#define EPM 496         // edges per molecule (C(32,2))
#define ATOM_OUT (NROWS*AT)  // 327680

// NOTE (round-3 lesson): __launch_bounds__ with a second argument clamped k4
// to 64 VGPRs and produced ~500 MB/dispatch of scratch spill traffic. Never
// pass a second argument.
// NOTE (round-4 lesson): wave-uniform s_load chains in the k4 inner loop left
// VALUBusy at 24% (latency-bound). This round: float4 LDS reads only.

// ---------------------------------------------------------------------------
// K1: Gram matrix M = Z^T Z (64x64) and column sums of Z.
// Grid 128 x 256 threads; 2 chunks of 128 rows through a 32KB LDS tile.
// ---------------------------------------------------------------------------
__global__ __launch_bounds__(256) void k1_moments(const float* __restrict__ z,
                                                  float* __restrict__ Msum,
                                                  float* __restrict__ sumz) {
    __shared__ __align__(16) float zs[128][64];   // 32 KB
    __shared__ float sred[4][64];
    const int tid = threadIdx.x;
    const int d0 = (tid >> 4) << 2;               // 0..60
    const int e0 = (tid & 15) << 2;
    const int d = tid & 63, rq = tid >> 6;
    float acc[4][4] = {};
    float colsum = 0.f;
    for (int chunk = 0; chunk < 2; ++chunk) {
        const int rowbase = (blockIdx.x * 2 + chunk) * 128;
        __syncthreads();                          // protect zs reuse across chunks
        const float4* zg4 = (const float4*)(z + rowbase * 64);
        float4* zs4 = (float4*)zs;
        #pragma unroll
        for (int k = 0; k < 8; ++k) zs4[tid + (k << 8)] = zg4[tid + (k << 8)];
        __syncthreads();
        for (int r = 0; r < 128; ++r) {
            float4 a4 = *(const float4*)&zs[r][d0];
            float4 b4 = *(const float4*)&zs[r][e0];
            float a[4] = {a4.x, a4.y, a4.z, a4.w};
            float b[4] = {b4.x, b4.y, b4.z, b4.w};
            #pragma unroll
            for (int i = 0; i < 4; ++i)
                #pragma unroll
                for (int jj = 0; jj < 4; ++jj) acc[i][jj] += a[i] * b[jj];
        }
        for (int r = rq * 32; r < rq * 32 + 32; ++r) colsum += zs[r][d];
    }
    #pragma unroll
    for (int i = 0; i < 4; ++i)
        #pragma unroll
        for (int jj = 0; jj < 4; ++jj)
            atomicAdd(&Msum[(d0 + i) * 64 + (e0 + jj)], acc[i][jj]);
    sred[rq][d] = colsum;
    __syncthreads();
    if (tid < 64)
        atomicAdd(&sumz[tid], sred[0][tid] + sred[1][tid] + sred[2][tid] + sred[3][tid]);
}

// ---------------------------------------------------------------------------
// K2W: (a) blocks 0..63: fold BN into per-channel affine h_bn = (z@W1)*a + c.
// (b) blocks 64..143: Wsym[t] = 0.5*(B[t]+B[t]^T)  (20480 elems).
// ---------------------------------------------------------------------------
__global__ __launch_bounds__(256) void k2w(const float* __restrict__ Msum,
                                           const float* __restrict__ sumz,
                                           const float* __restrict__ W1,
                                           const float* __restrict__ gamma,
                                           const float* __restrict__ beta,
                                           const float* __restrict__ bond,
                                           float* __restrict__ avec,
                                           float* __restrict__ cvec,
                                           float* __restrict__ Wsym) {
    const int tid = threadIdx.x;
    if (blockIdx.x >= 64) {
        int idx = ((int)blockIdx.x - 64) * 256 + tid;   // 0..20479
        int t = idx >> 12, rem = idx & 4095, dd = rem >> 6, c = rem & 63;
        Wsym[idx] = 0.5f * (bond[(t << 12) + (dd << 6) + c] +
                            bond[(t << 12) + (c << 6) + dd]);
        return;
    }
    const int wv = tid >> 6, d = tid & 63;
    const int j = blockIdx.x * 4 + wv;                  // 0..255
    const float wdj = W1[d * HD + j];
    float v = 0.f;
    for (int e = 0; e < 64; ++e) v += Msum[d * 64 + e] * W1[e * HD + j];
    float q = v * wdj;
    float s = sumz[d] * wdj;
    #pragma unroll
    for (int off = 32; off >= 1; off >>= 1) {
        q += __shfl_down(q, off);
        s += __shfl_down(s, off);
    }
    if (d == 0) {
        const float invN = 1.f / (float)NROWS;
        float mean = s * invN;
        float var = q * invN - mean * mean;
        float a = gamma[j] * rsqrtf(var + 1e-5f);
        avec[j] = a;
        cvec[j] = beta[j] - mean * a;
    }
}

// ---------------------------------------------------------------------------
// K3: fused MLP: atom_types = gelu((z@W1)*a + c) @ W2 + b2
// 1024 blocks x 32 rows, 256 threads. Thread tile: 2 rows x 16 channels.
// ---------------------------------------------------------------------------
__global__ __launch_bounds__(256) void k3_mlp(const float* __restrict__ z,
                                              const float* __restrict__ W1,
                                              const float* __restrict__ W2,
                                              const float* __restrict__ b2,
                                              const float* __restrict__ avec,
                                              const float* __restrict__ cvec,
                                              float* __restrict__ out_atom) {
    __shared__ __align__(16) float zsT[64][36];   // [d][row], 9.2 KB
    __shared__ __align__(16) float w1s[16][256];  // one 16-d chunk of W1, 16 KB
    __shared__ float w2s[256][11];                // stride 11 -> 2-way max (free)
    __shared__ float as[256], cs[256];
    const int tid = threadIdx.x;
    const int rowbase = blockIdx.x * 32;
    {   // stage z (32x64) transposed
        const float* zp = z + (size_t)(rowbase + (tid >> 3)) * 64 + (tid & 7) * 8;
        float4 v0 = *(const float4*)zp;
        float4 v1 = *(const float4*)(zp + 4);
        const int r = tid >> 3, dbase = (tid & 7) * 8;
        zsT[dbase + 0][r] = v0.x; zsT[dbase + 1][r] = v0.y;
        zsT[dbase + 2][r] = v0.z; zsT[dbase + 3][r] = v0.w;
        zsT[dbase + 4][r] = v1.x; zsT[dbase + 5][r] = v1.y;
        zsT[dbase + 6][r] = v1.z; zsT[dbase + 7][r] = v1.w;
    }
    for (int k = tid; k < HD * AT; k += 256) w2s[k / 10][k % 10] = W2[k];
    as[tid] = avec[tid]; cs[tid] = cvec[tid];

    const int rg = tid >> 4, cg = tid & 15;
    const int r0 = rg << 1;                       // 2 rows per thread
    float acc[2][4][4] = {};                      // [row][cblock][u]
    for (int ch = 0; ch < 4; ++ch) {
        __syncthreads();                          // w1s reuse (and staging on ch=0)
        #pragma unroll
        for (int k = 0; k < 16; ++k) {
            int idx = tid + (k << 8);
            ((float*)w1s)[idx] = W1[(ch << 12) + idx];
        }
        __syncthreads();
        #pragma unroll
        for (int dl = 0; dl < 16; ++dl) {
            float zr0 = zsT[(ch << 4) + dl][r0];
            float zr1 = zsT[(ch << 4) + dl][r0 + 1];
            #pragma unroll
            for (int cb = 0; cb < 4; ++cb) {
                float4 wv = *(const float4*)&w1s[dl][(cb << 6) + (cg << 2)];
                float wr[4] = {wv.x, wv.y, wv.z, wv.w};
                #pragma unroll
                for (int u = 0; u < 4; ++u) {
                    acc[0][cb][u] += zr0 * wr[u];
                    acc[1][cb][u] += zr1 * wr[u];
                }
            }
        }
    }
    float p[2][10] = {};
    #pragma unroll
    for (int cb = 0; cb < 4; ++cb)
        #pragma unroll
        for (int u = 0; u < 4; ++u) {
            const int c = (cb << 6) + (cg << 2) + u;
            const float a = as[c], cc = cs[c];
            #pragma unroll
            for (int ri = 0; ri < 2; ++ri) {
                float h = acc[ri][cb][u] * a + cc;
                h = 0.5f * h * (1.0f + erff(h * 0.70710678118654752f));
                #pragma unroll
                for (int o = 0; o < 10; ++o) p[ri][o] += h * w2s[c][o];
            }
        }
    #pragma unroll
    for (int m = 1; m <= 8; m <<= 1)
        #pragma unroll
        for (int ri = 0; ri < 2; ++ri)
            #pragma unroll
            for (int o = 0; o < 10; ++o) p[ri][o] += __shfl_xor(p[ri][o], m);
    if (cg == 0) {
        #pragma unroll
        for (int ri = 0; ri < 2; ++ri)
            for (int o = 0; o < 10; ++o)
                out_atom[(size_t)(rowbase + r0 + ri) * AT + o] = p[ri][o] + b2[o];
    }
}

// ---------------------------------------------------------------------------
// K4 v2: edges. Block = 2 molecules, 256 threads, grid 512. LDS ~51KB
// (3 blocks/CU, 12 waves/CU). No scalar loads; all operands via float4 LDS.
// Per bond type t (5 iterations, 2 barriers each):
//   stage Ws = Wsym[t] (16KB) into LDS with col-quad ^ row-quad XOR swizzle
//     (plain padded rows would be 8-way bank conflict on 16-lane d-group
//      reads; swizzled -> 2-way, free).
//   Phase A: U[j][d] = sum_c z[j][c] * Ws[d][c]  (row d of Wsym = column d by
//     symmetry). Thread tile 4j x 4d, k=c in float4 chunks: 8 ds_read_b128
//     per 64 FMA. Writes Us[j][d] as float4.
//   Phase B: accE[t][i][jp] += z_i[dq] . Us[jp][dq], thread tile 4i x 2j with
//     j-pair (j, j+16) (adjacent pair would be 4-way conflict; split is 2-way).
// Then per-thread softmax over 5 t, write in combinations order.
// ---------------------------------------------------------------------------
__global__ __launch_bounds__(256) void k4_edges(const float* __restrict__ z,
                                                const float* __restrict__ Wsym,
                                                float* __restrict__ out_edge) {
    __shared__ __align__(16) float zs[2][32][68];   // 17.4 KB
    __shared__ __align__(16) float WsL[4096];       // 16 KB, swizzled [r][cq^rq]
    __shared__ __align__(16) float Us[2][32][68];   // 17.4 KB
    const int tid = threadIdx.x;
    const int mol0 = blockIdx.x * 2;
    // stage zs (2 x 32 x 64) as float4, coalesced
    {
        const float4* zg4 = (const float4*)(z + (size_t)mol0 * 2048);
        #pragma unroll
        for (int k = 0; k < 4; ++k) {
            int e = tid + (k << 8);              // float4 index 0..1023
            int ml = e >> 9, r = (e >> 4) & 31, c4 = e & 15;
            *(float4*)&zs[ml][r][c4 << 2] = zg4[e];
        }
    }
    // phase-A ids: thread tile 4j x 4d
    const int am  = tid >> 7;                    // molecule 0/1
    const int aj0 = ((tid >> 4) & 7) << 2;       // 8 j-groups x 4
    const int adg = tid & 15;                    // 16 d-groups
    const int ad0 = adg << 2;
    // phase-B ids: thread tile 4i x {j, j+16}
    const int bm  = tid >> 7;
    const int i0  = ((tid >> 4) & 7) << 2;       // 8 i-groups x 4
    const int j1  = tid & 15, j2 = j1 + 16;
    float accE[5][4][2] = {};

    const float4* wg4 = (const float4*)Wsym;
    #pragma unroll
    for (int t = 0; t < 5; ++t) {
        // ---- stage Ws[t] swizzled (prev phase A done with Ws; B doesn't read it)
        #pragma unroll
        for (int k = 0; k < 4; ++k) {
            int e = tid + (k << 8);              // float4 index 0..1023
            int r = e >> 4, cq = e & 15;
            *(float4*)&WsL[(r << 6) + ((cq ^ (r >> 2)) << 2)] = wg4[(t << 10) + e];
        }
        __syncthreads();   // Ws ready; prev B done reading Us (A may overwrite)
        // ---- Phase A: 4j x 4d, k over 16 float4 chunks
        {
            float acc[4][4] = {};                // [jj][dd]
            #pragma unroll
            for (int cq = 0; cq < 16; ++cq) {
                float4 zv[4];
                #pragma unroll
                for (int jj = 0; jj < 4; ++jj)
                    zv[jj] = *(const float4*)&zs[am][aj0 + jj][cq << 2];
                const int swz = (cq ^ adg) << 2;
                #pragma unroll
                for (int dd = 0; dd < 4; ++dd) {
                    float4 wv = *(const float4*)&WsL[((ad0 + dd) << 6) + swz];
                    #pragma unroll
                    for (int jj = 0; jj < 4; ++jj)
                        acc[jj][dd] += zv[jj].x * wv.x + zv[jj].y * wv.y
                                     + zv[jj].z * wv.z + zv[jj].w * wv.w;
                }
            }
            #pragma unroll
            for (int jj = 0; jj < 4; ++jj) {
                float4 o; o.x = acc[jj][0]; o.y = acc[jj][1];
                o.z = acc[jj][2]; o.w = acc[jj][3];
                *(float4*)&Us[am][aj0 + jj][ad0] = o;
            }
        }
        __syncthreads();   // Us ready
        // ---- Phase B: 4i x {j1, j2}, k over 16 float4 chunks
        #pragma unroll
        for (int dq = 0; dq < 16; ++dq) {
            float4 u1 = *(const float4*)&Us[bm][j1][dq << 2];
            float4 u2 = *(const float4*)&Us[bm][j2][dq << 2];
            #pragma unroll
            for (int ri = 0; ri < 4; ++ri) {
                float4 zv = *(const float4*)&zs[bm][i0 + ri][dq << 2];
                accE[t][ri][0] += zv.x * u1.x + zv.y * u1.y + zv.z * u1.z + zv.w * u1.w;
                accE[t][ri][1] += zv.x * u2.x + zv.y * u2.y + zv.z * u2.z + zv.w * u2.w;
            }
        }
        // next iteration's Ws staging is safe without a barrier here: Ws is not
        // read by phase B, and phase A of this t (the only Ws reader) is
        // already complete for all threads (barrier above).
        __syncthreads();   // but Us must not be overwritten before B finishes
    }
    // softmax over 5 types + write (combinations order, i < j)
    #pragma unroll
    for (int ri = 0; ri < 4; ++ri) {
        #pragma unroll
        for (int rj = 0; rj < 2; ++rj) {
            const int i = i0 + ri, j = (rj == 0) ? j1 : j2;
            if (i < j) {
                float l0 = accE[0][ri][rj], l1 = accE[1][ri][rj], l2 = accE[2][ri][rj];
                float l3 = accE[3][ri][rj], l4 = accE[4][ri][rj];
                float m = fmaxf(fmaxf(fmaxf(l0, l1), fmaxf(l2, l3)), l4);
                float e0 = expf(l0 - m), e1 = expf(l1 - m), e2 = expf(l2 - m);
                float e3 = expf(l3 - m), e4 = expf(l4 - m);
                float inv = 1.0f / (e0 + e1 + e2 + e3 + e4);
                int p = 31 * i - ((i * (i - 1)) >> 1) + (j - i - 1);
                float* o = out_edge + (size_t)((mol0 + bm) * EPM + p) * 5;
                o[0] = e0 * inv; o[1] = e1 * inv; o[2] = e2 * inv;
                o[3] = e3 * inv; o[4] = e4 * inv;
            }
        }
    }
}

// ---------------------------------------------------------------------------
extern "C" void kernel_launch(void* const* d_in, const int* in_sizes, int n_in,
                              void* d_out, int out_size, void* d_ws, size_t ws_size,
                              hipStream_t stream) {
    (void)in_sizes; (void)n_in; (void)out_size; (void)ws_size;
    const float* z     = (const float*)d_in[0];
    const float* W1    = (const float*)d_in[1];
    // d_in[2] = b1 : cancels exactly in BN -> unused
    const float* gamma = (const float*)d_in[3];
    const float* beta  = (const float*)d_in[4];
    const float* W2    = (const float*)d_in[5];
    const float* b2    = (const float*)d_in[6];
    const float* bond  = (const float*)d_in[7];
    // d_in[8] = edge_index : deterministic combinations order, recomputed -> unused
    float* out = (float*)d_out;
    float* ws  = (float*)d_ws;

    float* Msum = ws;              // 4096
    float* sumz = ws + 4096;       // 64
    float* avec = ws + 4160;       // 256
    float* cvec = ws + 4416;       // 256
    float* Wsym = ws + 4672;       // 20480

    hipMemsetAsync(ws, 0, (4096 + 64) * sizeof(float), stream);
    k1_moments<<<128, 256, 0, stream>>>(z, Msum, sumz);
    k2w<<<144, 256, 0, stream>>>(Msum, sumz, W1, gamma, beta, bond, avec, cvec, Wsym);
    k3_mlp<<<1024, 256, 0, stream>>>(z, W1, W2, b2, avec, cvec, out);
    k4_edges<<<512, 256, 0, stream>>>(z, Wsym, out + ATOM_OUT);
}

// Round 9
// 213.725 us; speedup vs baseline: 3.7727x; 3.7727x over previous
//
#include <hip/hip_runtime.h>
#include <hip/hip_bf16.h>
#include <math.h>

// Problem constants
#define NM 1024         // molecules
#define NA 32           // atoms per molecule
#define ZD 64           // z dim
#define HD 256          // hidden
#define AT 10           // atom types
#define BT 5            // bond types
#define NROWS (NM*NA)   // 32768
#define EPM 496         // edges per molecule (C(32,2))
#define ATOM_OUT (NROWS*AT)  // 327680

// NOTE (round-3 lesson): __launch_bounds__ with a second argument clamped k4
// to 64 VGPRs -> ~500 MB/dispatch scratch spill. Never pass a second argument.
// NOTE (round-6 lesson): fully unrolling the 5x t-loop (stage+A+B body) blew
// live ranges past 256 VGPRs -> 1.36 GB/dispatch spill traffic. Keep the
// t-loop at #pragma unroll 1; keep all accumulator indexing compile-time.

// ---------------------------------------------------------------------------
// K1: Gram matrix M = Z^T Z (64x64) and column sums of Z.
// ---------------------------------------------------------------------------
__global__ __launch_bounds__(256) void k1_moments(const float* __restrict__ z,
                                                  float* __restrict__ Msum,
                                                  float* __restrict__ sumz) {
    __shared__ __align__(16) float zs[128][64];   // 32 KB
    __shared__ float sred[4][64];
    const int tid = threadIdx.x;
    const int d0 = (tid >> 4) << 2;               // 0..60
    const int e0 = (tid & 15) << 2;
    const int d = tid & 63, rq = tid >> 6;
    float acc[4][4] = {};
    float colsum = 0.f;
    for (int chunk = 0; chunk < 2; ++chunk) {
        const int rowbase = (blockIdx.x * 2 + chunk) * 128;
        __syncthreads();                          // protect zs reuse across chunks
        const float4* zg4 = (const float4*)(z + rowbase * 64);
        float4* zs4 = (float4*)zs;
        #pragma unroll
        for (int k = 0; k < 8; ++k) zs4[tid + (k << 8)] = zg4[tid + (k << 8)];
        __syncthreads();
        for (int r = 0; r < 128; ++r) {
            float4 a4 = *(const float4*)&zs[r][d0];
            float4 b4 = *(const float4*)&zs[r][e0];
            float a[4] = {a4.x, a4.y, a4.z, a4.w};
            float b[4] = {b4.x, b4.y, b4.z, b4.w};
            #pragma unroll
            for (int i = 0; i < 4; ++i)
                #pragma unroll
                for (int jj = 0; jj < 4; ++jj) acc[i][jj] += a[i] * b[jj];
        }
        for (int r = rq * 32; r < rq * 32 + 32; ++r) colsum += zs[r][d];
    }
    #pragma unroll
    for (int i = 0; i < 4; ++i)
        #pragma unroll
        for (int jj = 0; jj < 4; ++jj)
            atomicAdd(&Msum[(d0 + i) * 64 + (e0 + jj)], acc[i][jj]);
    sred[rq][d] = colsum;
    __syncthreads();
    if (tid < 64)
        atomicAdd(&sumz[tid], sred[0][tid] + sred[1][tid] + sred[2][tid] + sred[3][tid]);
}

// ---------------------------------------------------------------------------
// K2W: (a) blocks 0..63: fold BN into per-channel affine h_bn = (z@W1)*a + c.
// (b) blocks 64..143: Wsym[t] = 0.5*(B[t]+B[t]^T)  (20480 elems).
// ---------------------------------------------------------------------------
__global__ __launch_bounds__(256) void k2w(const float* __restrict__ Msum,
                                           const float* __restrict__ sumz,
                                           const float* __restrict__ W1,
                                           const float* __restrict__ gamma,
                                           const float* __restrict__ beta,
                                           const float* __restrict__ bond,
                                           float* __restrict__ avec,
                                           float* __restrict__ cvec,
                                           float* __restrict__ Wsym) {
    const int tid = threadIdx.x;
    if (blockIdx.x >= 64) {
        int idx = ((int)blockIdx.x - 64) * 256 + tid;   // 0..20479
        int t = idx >> 12, rem = idx & 4095, dd = rem >> 6, c = rem & 63;
        Wsym[idx] = 0.5f * (bond[(t << 12) + (dd << 6) + c] +
                            bond[(t << 12) + (c << 6) + dd]);
        return;
    }
    const int wv = tid >> 6, d = tid & 63;
    const int j = blockIdx.x * 4 + wv;                  // 0..255
    const float wdj = W1[d * HD + j];
    float v = 0.f;
    for (int e = 0; e < 64; ++e) v += Msum[d * 64 + e] * W1[e * HD + j];
    float q = v * wdj;
    float s = sumz[d] * wdj;
    #pragma unroll
    for (int off = 32; off >= 1; off >>= 1) {
        q += __shfl_down(q, off);
        s += __shfl_down(s, off);
    }
    if (d == 0) {
        const float invN = 1.f / (float)NROWS;
        float mean = s * invN;
        float var = q * invN - mean * mean;
        float a = gamma[j] * rsqrtf(var + 1e-5f);
        avec[j] = a;
        cvec[j] = beta[j] - mean * a;
    }
}

// ---------------------------------------------------------------------------
// K3: fused MLP: atom_types = gelu((z@W1)*a + c) @ W2 + b2
// 1024 blocks x 32 rows, 256 threads. Thread tile: 2 rows x 16 channels.
// ---------------------------------------------------------------------------
__global__ __launch_bounds__(256) void k3_mlp(const float* __restrict__ z,
                                              const float* __restrict__ W1,
                                              const float* __restrict__ W2,
                                              const float* __restrict__ b2,
                                              const float* __restrict__ avec,
                                              const float* __restrict__ cvec,
                                              float* __restrict__ out_atom) {
    __shared__ __align__(16) float zsT[64][36];   // [d][row], 9.2 KB
    __shared__ __align__(16) float w1s[16][256];  // one 16-d chunk of W1, 16 KB
    __shared__ float w2s[256][11];                // stride 11 -> 2-way max (free)
    __shared__ float as[256], cs[256];
    const int tid = threadIdx.x;
    const int rowbase = blockIdx.x * 32;
    {   // stage z (32x64) transposed
        const float* zp = z + (size_t)(rowbase + (tid >> 3)) * 64 + (tid & 7) * 8;
        float4 v0 = *(const float4*)zp;
        float4 v1 = *(const float4*)(zp + 4);
        const int r = tid >> 3, dbase = (tid & 7) * 8;
        zsT[dbase + 0][r] = v0.x; zsT[dbase + 1][r] = v0.y;
        zsT[dbase + 2][r] = v0.z; zsT[dbase + 3][r] = v0.w;
        zsT[dbase + 4][r] = v1.x; zsT[dbase + 5][r] = v1.y;
        zsT[dbase + 6][r] = v1.z; zsT[dbase + 7][r] = v1.w;
    }
    for (int k = tid; k < HD * AT; k += 256) w2s[k / 10][k % 10] = W2[k];
    as[tid] = avec[tid]; cs[tid] = cvec[tid];

    const int rg = tid >> 4, cg = tid & 15;
    const int r0 = rg << 1;                       // 2 rows per thread
    float acc[2][4][4] = {};                      // [row][cblock][u]
    for (int ch = 0; ch < 4; ++ch) {
        __syncthreads();                          // w1s reuse (and staging on ch=0)
        #pragma unroll
        for (int k = 0; k < 16; ++k) {
            int idx = tid + (k << 8);
            ((float*)w1s)[idx] = W1[(ch << 12) + idx];
        }
        __syncthreads();
        #pragma unroll
        for (int dl = 0; dl < 16; ++dl) {
            float zr0 = zsT[(ch << 4) + dl][r0];
            float zr1 = zsT[(ch << 4) + dl][r0 + 1];
            #pragma unroll
            for (int cb = 0; cb < 4; ++cb) {
                float4 wv = *(const float4*)&w1s[dl][(cb << 6) + (cg << 2)];
                float wr[4] = {wv.x, wv.y, wv.z, wv.w};
                #pragma unroll
                for (int u = 0; u < 4; ++u) {
                    acc[0][cb][u] += zr0 * wr[u];
                    acc[1][cb][u] += zr1 * wr[u];
                }
            }
        }
    }
    float p[2][10] = {};
    #pragma unroll
    for (int cb = 0; cb < 4; ++cb)
        #pragma unroll
        for (int u = 0; u < 4; ++u) {
            const int c = (cb << 6) + (cg << 2) + u;
            const float a = as[c], cc = cs[c];
            #pragma unroll
            for (int ri = 0; ri < 2; ++ri) {
                float h = acc[ri][cb][u] * a + cc;
                h = 0.5f * h * (1.0f + erff(h * 0.70710678118654752f));
                #pragma unroll
                for (int o = 0; o < 10; ++o) p[ri][o] += h * w2s[c][o];
            }
        }
    #pragma unroll
    for (int m = 1; m <= 8; m <<= 1)
        #pragma unroll
        for (int ri = 0; ri < 2; ++ri)
            #pragma unroll
            for (int o = 0; o < 10; ++o) p[ri][o] += __shfl_xor(p[ri][o], m);
    if (cg == 0) {
        #pragma unroll
        for (int ri = 0; ri < 2; ++ri)
            for (int o = 0; o < 10; ++o)
                out_atom[(size_t)(rowbase + r0 + ri) * AT + o] = p[ri][o] + b2[o];
    }
}

// ---------------------------------------------------------------------------
// K4 v3: edges. Same phase structure and bank-verified layouts as v2, but
// spill-proofed: t-loop forced to #pragma unroll 1, per-t logits accumulate
// in tmp[4][2] and are copied into five NAMED arrays via a wave-uniform
// if/else chain (all register indexing compile-time).
// Block = 2 molecules, 256 threads, grid 512. LDS ~51KB (3 blocks/CU).
// ---------------------------------------------------------------------------
__global__ __launch_bounds__(256) void k4_edges(const float* __restrict__ z,
                                                const float* __restrict__ Wsym,
                                                float* __restrict__ out_edge) {
    __shared__ __align__(16) float zs[2][32][68];   // 17.4 KB
    __shared__ __align__(16) float WsL[4096];       // 16 KB, swizzled [r][cq^rq]
    __shared__ __align__(16) float Us[2][32][68];   // 17.4 KB
    const int tid = threadIdx.x;
    const int mol0 = blockIdx.x * 2;
    // stage zs (2 x 32 x 64) as float4, coalesced
    {
        const float4* zg4 = (const float4*)(z + (size_t)mol0 * 2048);
        #pragma unroll
        for (int k = 0; k < 4; ++k) {
            int e = tid + (k << 8);              // float4 index 0..1023
            int ml = e >> 9, r = (e >> 4) & 31, c4 = e & 15;
            *(float4*)&zs[ml][r][c4 << 2] = zg4[e];
        }
    }
    // phase-A ids: thread tile 4j x 4d
    const int am  = tid >> 7;                    // molecule 0/1 (wave-uniform)
    const int aj0 = ((tid >> 4) & 7) << 2;       // 8 j-groups x 4
    const int adg = tid & 15;                    // 16 d-groups
    const int ad0 = adg << 2;
    // phase-B ids: thread tile 4i x {j, j+16}
    const int bm  = tid >> 7;
    const int i0  = ((tid >> 4) & 7) << 2;       // 8 i-groups x 4
    const int j1  = tid & 15, j2 = j1 + 16;
    // five NAMED per-t logit tiles (compile-time indexed everywhere)
    float e0a[4][2] = {}, e1a[4][2] = {}, e2a[4][2] = {}, e3a[4][2] = {}, e4a[4][2] = {};

    const float4* wg4 = (const float4*)Wsym;
    #pragma unroll 1
    for (int t = 0; t < 5; ++t) {
        // ---- stage Ws[t] swizzled ----
        #pragma unroll
        for (int k = 0; k < 4; ++k) {
            int e = tid + (k << 8);              // float4 index 0..1023
            int r = e >> 4, cq = e & 15;
            *(float4*)&WsL[(r << 6) + ((cq ^ (r >> 2)) << 2)] = wg4[(t << 10) + e];
        }
        __syncthreads();   // Ws ready; prev B done reading Us (A may overwrite)
        // ---- Phase A: 4j x 4d, k over 16 float4 chunks ----
        {
            float acc[4][4] = {};                // [jj][dd]
            #pragma unroll 4
            for (int cq = 0; cq < 16; ++cq) {
                float4 zv[4];
                #pragma unroll
                for (int jj = 0; jj < 4; ++jj)
                    zv[jj] = *(const float4*)&zs[am][aj0 + jj][cq << 2];
                const int swz = (cq ^ adg) << 2;
                #pragma unroll
                for (int dd = 0; dd < 4; ++dd) {
                    float4 wv = *(const float4*)&WsL[((ad0 + dd) << 6) + swz];
                    #pragma unroll
                    for (int jj = 0; jj < 4; ++jj)
                        acc[jj][dd] += zv[jj].x * wv.x + zv[jj].y * wv.y
                                     + zv[jj].z * wv.z + zv[jj].w * wv.w;
                }
            }
            #pragma unroll
            for (int jj = 0; jj < 4; ++jj) {
                float4 o; o.x = acc[jj][0]; o.y = acc[jj][1];
                o.z = acc[jj][2]; o.w = acc[jj][3];
                *(float4*)&Us[am][aj0 + jj][ad0] = o;
            }
        }
        __syncthreads();   // Us ready
        // ---- Phase B: 4i x {j1, j2} into tmp ----
        float tmp[4][2] = {};
        #pragma unroll 4
        for (int dq = 0; dq < 16; ++dq) {
            float4 u1 = *(const float4*)&Us[bm][j1][dq << 2];
            float4 u2 = *(const float4*)&Us[bm][j2][dq << 2];
            #pragma unroll
            for (int ri = 0; ri < 4; ++ri) {
                float4 zv = *(const float4*)&zs[bm][i0 + ri][dq << 2];
                tmp[ri][0] += zv.x * u1.x + zv.y * u1.y + zv.z * u1.z + zv.w * u1.w;
                tmp[ri][1] += zv.x * u2.x + zv.y * u2.y + zv.z * u2.z + zv.w * u2.w;
            }
        }
        // copy into the named per-t tile (t is wave-uniform -> cheap branches)
        if (t == 0) {
            #pragma unroll
            for (int ri = 0; ri < 4; ++ri) { e0a[ri][0] = tmp[ri][0]; e0a[ri][1] = tmp[ri][1]; }
        } else if (t == 1) {
            #pragma unroll
            for (int ri = 0; ri < 4; ++ri) { e1a[ri][0] = tmp[ri][0]; e1a[ri][1] = tmp[ri][1]; }
        } else if (t == 2) {
            #pragma unroll
            for (int ri = 0; ri < 4; ++ri) { e2a[ri][0] = tmp[ri][0]; e2a[ri][1] = tmp[ri][1]; }
        } else if (t == 3) {
            #pragma unroll
            for (int ri = 0; ri < 4; ++ri) { e3a[ri][0] = tmp[ri][0]; e3a[ri][1] = tmp[ri][1]; }
        } else {
            #pragma unroll
            for (int ri = 0; ri < 4; ++ri) { e4a[ri][0] = tmp[ri][0]; e4a[ri][1] = tmp[ri][1]; }
        }
        __syncthreads();   // Us must not be overwritten before B finishes
    }
    // softmax over 5 types + write (combinations order, i < j)
    #pragma unroll
    for (int ri = 0; ri < 4; ++ri) {
        #pragma unroll
        for (int rj = 0; rj < 2; ++rj) {
            const int i = i0 + ri, j = (rj == 0) ? j1 : j2;
            if (i < j) {
                float l0 = e0a[ri][rj], l1 = e1a[ri][rj], l2 = e2a[ri][rj];
                float l3 = e3a[ri][rj], l4 = e4a[ri][rj];
                float m = fmaxf(fmaxf(fmaxf(l0, l1), fmaxf(l2, l3)), l4);
                float x0 = expf(l0 - m), x1 = expf(l1 - m), x2 = expf(l2 - m);
                float x3 = expf(l3 - m), x4 = expf(l4 - m);
                float inv = 1.0f / (x0 + x1 + x2 + x3 + x4);
                int p = 31 * i - ((i * (i - 1)) >> 1) + (j - i - 1);
                float* o = out_edge + (size_t)((mol0 + bm) * EPM + p) * 5;
                o[0] = x0 * inv; o[1] = x1 * inv; o[2] = x2 * inv;
                o[3] = x3 * inv; o[4] = x4 * inv;
            }
        }
    }
}

// ---------------------------------------------------------------------------
extern "C" void kernel_launch(void* const* d_in, const int* in_sizes, int n_in,
                              void* d_out, int out_size, void* d_ws, size_t ws_size,
                              hipStream_t stream) {
    (void)in_sizes; (void)n_in; (void)out_size; (void)ws_size;
    const float* z     = (const float*)d_in[0];
    const float* W1    = (const float*)d_in[1];
    // d_in[2] = b1 : cancels exactly in BN -> unused
    const float* gamma = (const float*)d_in[3];
    const float* beta  = (const float*)d_in[4];
    const float* W2    = (const float*)d_in[5];
    const float* b2    = (const float*)d_in[6];
    const float* bond  = (const float*)d_in[7];
    // d_in[8] = edge_index : deterministic combinations order, recomputed -> unused
    float* out = (float*)d_out;
    float* ws  = (float*)d_ws;

    float* Msum = ws;              // 4096
    float* sumz = ws + 4096;       // 64
    float* avec = ws + 4160;       // 256
    float* cvec = ws + 4416;       // 256
    float* Wsym = ws + 4672;       // 20480

    hipMemsetAsync(ws, 0, (4096 + 64) * sizeof(float), stream);
    k1_moments<<<128, 256, 0, stream>>>(z, Msum, sumz);
    k2w<<<144, 256, 0, stream>>>(Msum, sumz, W1, gamma, beta, bond, avec, cvec, Wsym);
    k3_mlp<<<1024, 256, 0, stream>>>(z, W1, W2, b2, avec, cvec, out);
    k4_edges<<<512, 256, 0, stream>>>(z, Wsym, out + ATOM_OUT);
}

// Round 10
// 204.690 us; speedup vs baseline: 3.9392x; 1.0441x over previous
//
#include <hip/hip_runtime.h>
#include <hip/hip_bf16.h>
#include <math.h>

// Problem constants
#define NM 1024         // molecules
#define NA 32           // atoms per molecule
#define ZD 64           // z dim
#define HD 256          // hidden
#define AT 10           // atom types
#define BT 5            // bond types
#define NROWS (NM*NA)   // 32768
#define EPM 496         // edges per molecule (C(32,2))
#define ATOM_OUT (NROWS*AT)  // 327680

// NOTE (round-3 lesson): __launch_bounds__ with a second argument clamped k4
// to 64 VGPRs -> ~500 MB/dispatch scratch spill. Never pass a second argument.
// NOTE (round-6 lesson): fully unrolling the 5x t-loop (stage+A+B body) blew
// live ranges past 256 VGPRs -> 1.36 GB/dispatch spill traffic. Keep big
// multi-phase loops at #pragma unroll 1; keep register indexing compile-time.
// NOTE (round-9 lesson): k3's zsT transpose staging had stride 36 (8*36 % 32
// == 0 -> 8-way write conflict, 1.72M cycles) and the transpose was pointless:
// GEMM reads are 16-lane broadcasts either way. Row-major + odd stride.

// ---------------------------------------------------------------------------
// K1: Gram matrix M = Z^T Z (64x64) and column sums of Z.
// ---------------------------------------------------------------------------
__global__ __launch_bounds__(256) void k1_moments(const float* __restrict__ z,
                                                  float* __restrict__ Msum,
                                                  float* __restrict__ sumz) {
    __shared__ __align__(16) float zs[128][64];   // 32 KB
    __shared__ float sred[4][64];
    const int tid = threadIdx.x;
    const int d0 = (tid >> 4) << 2;               // 0..60
    const int e0 = (tid & 15) << 2;
    const int d = tid & 63, rq = tid >> 6;
    float acc[4][4] = {};
    float colsum = 0.f;
    for (int chunk = 0; chunk < 2; ++chunk) {
        const int rowbase = (blockIdx.x * 2 + chunk) * 128;
        __syncthreads();                          // protect zs reuse across chunks
        const float4* zg4 = (const float4*)(z + rowbase * 64);
        float4* zs4 = (float4*)zs;
        #pragma unroll
        for (int k = 0; k < 8; ++k) zs4[tid + (k << 8)] = zg4[tid + (k << 8)];
        __syncthreads();
        for (int r = 0; r < 128; ++r) {
            float4 a4 = *(const float4*)&zs[r][d0];
            float4 b4 = *(const float4*)&zs[r][e0];
            float a[4] = {a4.x, a4.y, a4.z, a4.w};
            float b[4] = {b4.x, b4.y, b4.z, b4.w};
            #pragma unroll
            for (int i = 0; i < 4; ++i)
                #pragma unroll
                for (int jj = 0; jj < 4; ++jj) acc[i][jj] += a[i] * b[jj];
        }
        for (int r = rq * 32; r < rq * 32 + 32; ++r) colsum += zs[r][d];
    }
    #pragma unroll
    for (int i = 0; i < 4; ++i)
        #pragma unroll
        for (int jj = 0; jj < 4; ++jj)
            atomicAdd(&Msum[(d0 + i) * 64 + (e0 + jj)], acc[i][jj]);
    sred[rq][d] = colsum;
    __syncthreads();
    if (tid < 64)
        atomicAdd(&sumz[tid], sred[0][tid] + sred[1][tid] + sred[2][tid] + sred[3][tid]);
}

// ---------------------------------------------------------------------------
// K2W: (a) blocks 0..63: fold BN into per-channel affine h_bn = (z@W1)*a + c.
// (b) blocks 64..143: Wsym[t] = 0.5*(B[t]+B[t]^T)  (20480 elems).
// ---------------------------------------------------------------------------
__global__ __launch_bounds__(256) void k2w(const float* __restrict__ Msum,
                                           const float* __restrict__ sumz,
                                           const float* __restrict__ W1,
                                           const float* __restrict__ gamma,
                                           const float* __restrict__ beta,
                                           const float* __restrict__ bond,
                                           float* __restrict__ avec,
                                           float* __restrict__ cvec,
                                           float* __restrict__ Wsym) {
    const int tid = threadIdx.x;
    if (blockIdx.x >= 64) {
        int idx = ((int)blockIdx.x - 64) * 256 + tid;   // 0..20479
        int t = idx >> 12, rem = idx & 4095, dd = rem >> 6, c = rem & 63;
        Wsym[idx] = 0.5f * (bond[(t << 12) + (dd << 6) + c] +
                            bond[(t << 12) + (c << 6) + dd]);
        return;
    }
    const int wv = tid >> 6, d = tid & 63;
    const int j = blockIdx.x * 4 + wv;                  // 0..255
    const float wdj = W1[d * HD + j];
    float v = 0.f;
    for (int e = 0; e < 64; ++e) v += Msum[d * 64 + e] * W1[e * HD + j];
    float q = v * wdj;
    float s = sumz[d] * wdj;
    #pragma unroll
    for (int off = 32; off >= 1; off >>= 1) {
        q += __shfl_down(q, off);
        s += __shfl_down(s, off);
    }
    if (d == 0) {
        const float invN = 1.f / (float)NROWS;
        float mean = s * invN;
        float var = q * invN - mean * mean;
        float a = gamma[j] * rsqrtf(var + 1e-5f);
        avec[j] = a;
        cvec[j] = beta[j] - mean * a;
    }
}

// ---------------------------------------------------------------------------
// K3 v2: fused MLP: atom_types = gelu((z@W1)*a + c) @ W2 + b2
// 512 blocks x 64 rows, 256 threads. Thread tile: 4 rows x 16 channels.
// z staged ROW-MAJOR stride 65 (odd): coalesced float4 staging writes with no
// bank conflicts (round-9 fix), GEMM reads are 16-lane broadcasts.
// LDS ~46KB -> 3 blocks/CU capacity. W1 staging amortized over 2x the rows.
// ---------------------------------------------------------------------------
__global__ __launch_bounds__(256) void k3_mlp(const float* __restrict__ z,
                                              const float* __restrict__ W1,
                                              const float* __restrict__ W2,
                                              const float* __restrict__ b2,
                                              const float* __restrict__ avec,
                                              const float* __restrict__ cvec,
                                              float* __restrict__ out_atom) {
    __shared__ float zs[64][65];                  // row-major, odd stride; 16.6 KB
    __shared__ __align__(16) float w1s[16][256];  // one 16-d chunk of W1, 16 KB
    __shared__ float w2s[256][11];                // stride 11 -> 2-way max (free)
    __shared__ float as[256], cs[256];
    const int tid = threadIdx.x;
    const int rowbase = blockIdx.x * 64;
    {   // stage z (64x64) row-major: 1024 float4, 4 per thread, coalesced
        const float4* zg4 = (const float4*)(z + (size_t)rowbase * 64);
        #pragma unroll
        for (int k = 0; k < 4; ++k) {
            int e = tid + (k << 8);               // 0..1023
            int r = e >> 4, c4 = e & 15;
            *(float4*)&zs[r][c4 << 2] = zg4[e];
        }
    }
    for (int k = tid; k < HD * AT; k += 256) w2s[k / 10][k % 10] = W2[k];
    as[tid] = avec[tid]; cs[tid] = cvec[tid];

    const int rg = tid >> 4, cg = tid & 15;
    const int r0 = rg << 2;                       // 4 rows per thread
    float acc[4][4][4] = {};                      // [row][cblock][u]
    for (int ch = 0; ch < 4; ++ch) {
        __syncthreads();                          // w1s reuse (and staging on ch=0)
        #pragma unroll
        for (int k = 0; k < 16; ++k) {
            int idx = tid + (k << 8);
            ((float*)w1s)[idx] = W1[(ch << 12) + idx];
        }
        __syncthreads();
        #pragma unroll
        for (int dl = 0; dl < 16; ++dl) {
            const int gd = (ch << 4) + dl;
            float zr[4];
            #pragma unroll
            for (int ri = 0; ri < 4; ++ri) zr[ri] = zs[r0 + ri][gd];  // broadcast reads
            #pragma unroll
            for (int cb = 0; cb < 4; ++cb) {
                float4 wv = *(const float4*)&w1s[dl][(cb << 6) + (cg << 2)];
                float wr[4] = {wv.x, wv.y, wv.z, wv.w};
                #pragma unroll
                for (int ri = 0; ri < 4; ++ri)
                    #pragma unroll
                    for (int u = 0; u < 4; ++u) acc[ri][cb][u] += zr[ri] * wr[u];
            }
        }
    }
    // epilogue: affine + exact gelu + GEMM2 partials
    float p[4][10] = {};
    #pragma unroll
    for (int cb = 0; cb < 4; ++cb)
        #pragma unroll
        for (int u = 0; u < 4; ++u) {
            const int c = (cb << 6) + (cg << 2) + u;
            const float a = as[c], cc = cs[c];
            #pragma unroll
            for (int ri = 0; ri < 4; ++ri) {
                float h = acc[ri][cb][u] * a + cc;
                h = 0.5f * h * (1.0f + erff(h * 0.70710678118654752f));
                #pragma unroll
                for (int o = 0; o < 10; ++o) p[ri][o] += h * w2s[c][o];
            }
        }
    #pragma unroll
    for (int m = 1; m <= 8; m <<= 1)
        #pragma unroll
        for (int ri = 0; ri < 4; ++ri)
            #pragma unroll
            for (int o = 0; o < 10; ++o) p[ri][o] += __shfl_xor(p[ri][o], m);
    if (cg == 0) {
        #pragma unroll
        for (int ri = 0; ri < 4; ++ri)
            for (int o = 0; o < 10; ++o)
                out_atom[(size_t)(rowbase + r0 + ri) * AT + o] = p[ri][o] + b2[o];
    }
}

// ---------------------------------------------------------------------------
// K4 v3: edges (unchanged from round 9 — spill-free, <62us steady state).
// Block = 2 molecules, 256 threads, grid 512. LDS ~51KB (3 blocks/CU).
// t-loop at #pragma unroll 1; named per-t accumulator tiles.
// ---------------------------------------------------------------------------
__global__ __launch_bounds__(256) void k4_edges(const float* __restrict__ z,
                                                const float* __restrict__ Wsym,
                                                float* __restrict__ out_edge) {
    __shared__ __align__(16) float zs[2][32][68];   // 17.4 KB
    __shared__ __align__(16) float WsL[4096];       // 16 KB, swizzled [r][cq^rq]
    __shared__ __align__(16) float Us[2][32][68];   // 17.4 KB
    const int tid = threadIdx.x;
    const int mol0 = blockIdx.x * 2;
    // stage zs (2 x 32 x 64) as float4, coalesced
    {
        const float4* zg4 = (const float4*)(z + (size_t)mol0 * 2048);
        #pragma unroll
        for (int k = 0; k < 4; ++k) {
            int e = tid + (k << 8);              // float4 index 0..1023
            int ml = e >> 9, r = (e >> 4) & 31, c4 = e & 15;
            *(float4*)&zs[ml][r][c4 << 2] = zg4[e];
        }
    }
    // phase-A ids: thread tile 4j x 4d
    const int am  = tid >> 7;                    // molecule 0/1 (wave-uniform)
    const int aj0 = ((tid >> 4) & 7) << 2;       // 8 j-groups x 4
    const int adg = tid & 15;                    // 16 d-groups
    const int ad0 = adg << 2;
    // phase-B ids: thread tile 4i x {j, j+16}
    const int bm  = tid >> 7;
    const int i0  = ((tid >> 4) & 7) << 2;       // 8 i-groups x 4
    const int j1  = tid & 15, j2 = j1 + 16;
    // five NAMED per-t logit tiles (compile-time indexed everywhere)
    float e0a[4][2] = {}, e1a[4][2] = {}, e2a[4][2] = {}, e3a[4][2] = {}, e4a[4][2] = {};

    const float4* wg4 = (const float4*)Wsym;
    #pragma unroll 1
    for (int t = 0; t < 5; ++t) {
        // ---- stage Ws[t] swizzled ----
        #pragma unroll
        for (int k = 0; k < 4; ++k) {
            int e = tid + (k << 8);              // float4 index 0..1023
            int r = e >> 4, cq = e & 15;
            *(float4*)&WsL[(r << 6) + ((cq ^ (r >> 2)) << 2)] = wg4[(t << 10) + e];
        }
        __syncthreads();   // Ws ready; prev B done reading Us (A may overwrite)
        // ---- Phase A: 4j x 4d, k over 16 float4 chunks ----
        {
            float acc[4][4] = {};                // [jj][dd]
            #pragma unroll 4
            for (int cq = 0; cq < 16; ++cq) {
                float4 zv[4];
                #pragma unroll
                for (int jj = 0; jj < 4; ++jj)
                    zv[jj] = *(const float4*)&zs[am][aj0 + jj][cq << 2];
                const int swz = (cq ^ adg) << 2;
                #pragma unroll
                for (int dd = 0; dd < 4; ++dd) {
                    float4 wv = *(const float4*)&WsL[((ad0 + dd) << 6) + swz];
                    #pragma unroll
                    for (int jj = 0; jj < 4; ++jj)
                        acc[jj][dd] += zv[jj].x * wv.x + zv[jj].y * wv.y
                                     + zv[jj].z * wv.z + zv[jj].w * wv.w;
                }
            }
            #pragma unroll
            for (int jj = 0; jj < 4; ++jj) {
                float4 o; o.x = acc[jj][0]; o.y = acc[jj][1];
                o.z = acc[jj][2]; o.w = acc[jj][3];
                *(float4*)&Us[am][aj0 + jj][ad0] = o;
            }
        }
        __syncthreads();   // Us ready
        // ---- Phase B: 4i x {j1, j2} into tmp ----
        float tmp[4][2] = {};
        #pragma unroll 4
        for (int dq = 0; dq < 16; ++dq) {
            float4 u1 = *(const float4*)&Us[bm][j1][dq << 2];
            float4 u2 = *(const float4*)&Us[bm][j2][dq << 2];
            #pragma unroll
            for (int ri = 0; ri < 4; ++ri) {
                float4 zv = *(const float4*)&zs[bm][i0 + ri][dq << 2];
                tmp[ri][0] += zv.x * u1.x + zv.y * u1.y + zv.z * u1.z + zv.w * u1.w;
                tmp[ri][1] += zv.x * u2.x + zv.y * u2.y + zv.z * u2.z + zv.w * u2.w;
            }
        }
        // copy into the named per-t tile (t is wave-uniform -> cheap branches)
        if (t == 0) {
            #pragma unroll
            for (int ri = 0; ri < 4; ++ri) { e0a[ri][0] = tmp[ri][0]; e0a[ri][1] = tmp[ri][1]; }
        } else if (t == 1) {
            #pragma unroll
            for (int ri = 0; ri < 4; ++ri) { e1a[ri][0] = tmp[ri][0]; e1a[ri][1] = tmp[ri][1]; }
        } else if (t == 2) {
            #pragma unroll
            for (int ri = 0; ri < 4; ++ri) { e2a[ri][0] = tmp[ri][0]; e2a[ri][1] = tmp[ri][1]; }
        } else if (t == 3) {
            #pragma unroll
            for (int ri = 0; ri < 4; ++ri) { e3a[ri][0] = tmp[ri][0]; e3a[ri][1] = tmp[ri][1]; }
        } else {
            #pragma unroll
            for (int ri = 0; ri < 4; ++ri) { e4a[ri][0] = tmp[ri][0]; e4a[ri][1] = tmp[ri][1]; }
        }
        __syncthreads();   // Us must not be overwritten before B finishes
    }
    // softmax over 5 types + write (combinations order, i < j)
    #pragma unroll
    for (int ri = 0; ri < 4; ++ri) {
        #pragma unroll
        for (int rj = 0; rj < 2; ++rj) {
            const int i = i0 + ri, j = (rj == 0) ? j1 : j2;
            if (i < j) {
                float l0 = e0a[ri][rj], l1 = e1a[ri][rj], l2 = e2a[ri][rj];
                float l3 = e3a[ri][rj], l4 = e4a[ri][rj];
                float m = fmaxf(fmaxf(fmaxf(l0, l1), fmaxf(l2, l3)), l4);
                float x0 = expf(l0 - m), x1 = expf(l1 - m), x2 = expf(l2 - m);
                float x3 = expf(l3 - m), x4 = expf(l4 - m);
                float inv = 1.0f / (x0 + x1 + x2 + x3 + x4);
                int p = 31 * i - ((i * (i - 1)) >> 1) + (j - i - 1);
                float* o = out_edge + (size_t)((mol0 + bm) * EPM + p) * 5;
                o[0] = x0 * inv; o[1] = x1 * inv; o[2] = x2 * inv;
                o[3] = x3 * inv; o[4] = x4 * inv;
            }
        }
    }
}

// ---------------------------------------------------------------------------
extern "C" void kernel_launch(void* const* d_in, const int* in_sizes, int n_in,
                              void* d_out, int out_size, void* d_ws, size_t ws_size,
                              hipStream_t stream) {
    (void)in_sizes; (void)n_in; (void)out_size; (void)ws_size;
    const float* z     = (const float*)d_in[0];
    const float* W1    = (const float*)d_in[1];
    // d_in[2] = b1 : cancels exactly in BN -> unused
    const float* gamma = (const float*)d_in[3];
    const float* beta  = (const float*)d_in[4];
    const float* W2    = (const float*)d_in[5];
    const float* b2    = (const float*)d_in[6];
    const float* bond  = (const float*)d_in[7];
    // d_in[8] = edge_index : deterministic combinations order, recomputed -> unused
    float* out = (float*)d_out;
    float* ws  = (float*)d_ws;

    float* Msum = ws;              // 4096
    float* sumz = ws + 4096;       // 64
    float* avec = ws + 4160;       // 256
    float* cvec = ws + 4416;       // 256
    float* Wsym = ws + 4672;       // 20480

    hipMemsetAsync(ws, 0, (4096 + 64) * sizeof(float), stream);
    k1_moments<<<128, 256, 0, stream>>>(z, Msum, sumz);
    k2w<<<144, 256, 0, stream>>>(Msum, sumz, W1, gamma, beta, bond, avec, cvec, Wsym);
    k3_mlp<<<512, 256, 0, stream>>>(z, W1, W2, b2, avec, cvec, out);
    k4_edges<<<512, 256, 0, stream>>>(z, Wsym, out + ATOM_OUT);
}